// Round 8
// baseline (321.053 us; speedup 1.0000x reference)
//
#include <hip/hip_runtime.h>
#include <stdint.h>

#define MM 8
#define KK 8192
#define NN 8192
#define KC 128                 // k rows per gemm block
#define KSPLIT (KK / KC)       // 64 partial slabs
#define G 4                    // k-steps per prefetch group
#define FP8MAXV 448.0f

typedef float f32x4 __attribute__((ext_vector_type(4)));
typedef unsigned int uint32_tt;

// ws layout (floats):
//   [0..7]                      x_scale_inv per row
//   [64 .. 64+KK*MM/2)          xqT as bf16 (ushort), [k][m] packed: KK*MM*2 B
//   [PART_OFF ..)               partials [KSPLIT][MM][NN]  (16 MB)
#define XQT_OFF 64
#define PART_OFF (XQT_OFF + (KK * MM) / 2)

// ---------------------------------------------------------------------------
// Bit-exact RNE f32 -> fp8 e4m3fn -> f32 (|v| <= 448).
// ---------------------------------------------------------------------------
__device__ __forceinline__ float fp8_e4m3_round(float v) {
    uint32_t u = __float_as_uint(v);
    uint32_t mag = u & 0x7fffffffu;
    if (mag >= 0x3C800000u) {            // |v| >= 2^-6 : normal e4m3
        uint32_t lsb = (u >> 20) & 1u;
        uint32_t r = u + 0x0007FFFFu + lsb;
        r &= 0xFFF00000u;
        return __uint_as_float(r);
    }
    return rintf(v * 512.0f) * (1.0f / 512.0f);   // subnormal quantum 2^-9
}

// ---------------------------------------------------------------------------
// Kernel 1: per-row amax -> scale; quantize x; store xqT[k][m] as bf16.
// fp8 e4m3 values have <=3 mantissa bits -> EXACTLY representable in bf16,
// so (bits >> 16) truncation is lossless here.
// ---------------------------------------------------------------------------
__global__ __launch_bounds__(256) void prep_kernel(const float* __restrict__ x,
                                                   float* __restrict__ ws) {
    const int m = blockIdx.x;
    const int tid = threadIdx.x;
    const float* row = x + (size_t)m * KK;

    float amax = 0.0f;
    for (int k = tid * 4; k < KK; k += 256 * 4) {
        f32x4 v = *(const f32x4*)(row + k);
        amax = fmaxf(amax, fmaxf(fmaxf(fabsf(v.x), fabsf(v.y)),
                                 fmaxf(fabsf(v.z), fabsf(v.w))));
    }
#pragma unroll
    for (int off = 32; off >= 1; off >>= 1)
        amax = fmaxf(amax, __shfl_xor(amax, off, 64));

    __shared__ float sred[4];
    __shared__ float sscale;
    if ((tid & 63) == 0) sred[tid >> 6] = amax;
    __syncthreads();
    if (tid == 0) {
        float a = fmaxf(fmaxf(sred[0], sred[1]), fmaxf(sred[2], sred[3]));
        float scale = (a > 0.0f) ? (FP8MAXV / a) : 1.0f;
        sscale = scale;
        ws[m] = 1.0f / scale;
    }
    __syncthreads();
    const float scale = sscale;

    unsigned short* xqT = (unsigned short*)(ws + XQT_OFF);
    for (int k = tid; k < KK; k += 256) {
        float q = fp8_e4m3_round(row[k] * scale);
        xqT[(size_t)k * MM + m] = (unsigned short)(__float_as_uint(q) >> 16);
    }
}

// ---------------------------------------------------------------------------
// Kernel 2 (R7): max-TLP split-K GEMV. 1 col/thread, scalar 4 B W loads,
// KC=128, grid (NN/256, KSPLIT) = (32,64) = 2048 blocks = 8 blocks/CU =
// 32 waves/CU (LB(256,8) caps VGPR at 64). Activations: bf16-packed in LDS,
// ONE ds_read_b128 per k-step delivers all 8 m-values (lgkmcnt path, never
// touches the vmcnt queue pacing W). W register-double-buffered (G=4).
// ---------------------------------------------------------------------------
__global__ __launch_bounds__(256, 8) void gemm_partial(const float* __restrict__ W,
                                                       const float* __restrict__ wsinv,
                                                       const float* __restrict__ ws,
                                                       float* __restrict__ part) {
    const int tid = threadIdx.x;
    const int n   = blockIdx.x * 256 + tid;
    const int c   = blockIdx.y;
    const int k0  = c * KC;

    __shared__ uint4 sxq[KC * MM / 8];   // 2 KB: one uint4 = 8 bf16 per k
    if (tid < KC * MM / 8)
        sxq[tid] = ((const uint4*)((const unsigned short*)(ws + XQT_OFF) +
                                   (size_t)k0 * MM))[tid];
    __syncthreads();

    float acc[MM];
#pragma unroll
    for (int m = 0; m < MM; ++m) acc[m] = 0.0f;

    const float* __restrict__ Wp = W + (size_t)k0 * NN + n;

    float wA[G], wB[G];
    auto loadg = [&](float (&buf)[G], int kbase) {
#pragma unroll
        for (int j = 0; j < G; ++j)
            buf[j] = Wp[(size_t)(kbase + j) * NN];
    };
    auto compute = [&](float (&buf)[G], int kbase) {
#pragma unroll
        for (int j = 0; j < G; ++j) {
            uint4 a = sxq[kbase + j];            // 8 bf16 activations
            float w = buf[j];
            acc[0] = fmaf(w, __uint_as_float(a.x << 16),          acc[0]);
            acc[1] = fmaf(w, __uint_as_float(a.x & 0xFFFF0000u),  acc[1]);
            acc[2] = fmaf(w, __uint_as_float(a.y << 16),          acc[2]);
            acc[3] = fmaf(w, __uint_as_float(a.y & 0xFFFF0000u),  acc[3]);
            acc[4] = fmaf(w, __uint_as_float(a.z << 16),          acc[4]);
            acc[5] = fmaf(w, __uint_as_float(a.z & 0xFFFF0000u),  acc[5]);
            acc[6] = fmaf(w, __uint_as_float(a.w << 16),          acc[6]);
            acc[7] = fmaf(w, __uint_as_float(a.w & 0xFFFF0000u),  acc[7]);
        }
    };

    loadg(wA, 0 * G);
    loadg(wB, 1 * G);
    int g = 0;
    for (; g + 2 < KC / G; g += 2) {
        compute(wA, (g + 0) * G);
        loadg(wA, (g + 2) * G);
        compute(wB, (g + 1) * G);
        loadg(wB, (g + 3) * G);
    }
    compute(wA, (g + 0) * G);
    compute(wB, (g + 1) * G);

    const float wsn = wsinv[n];
    float* p = part + ((size_t)c * MM) * NN + n;
#pragma unroll
    for (int m = 0; m < MM; ++m)
        p[(size_t)m * NN] = acc[m] * (ws[m] * wsn);
}

// ---------------------------------------------------------------------------
// Kernel 3: reduce KSPLIT partials + bias -> out.
// ---------------------------------------------------------------------------
__global__ __launch_bounds__(256) void reduce_kernel(const float* __restrict__ part,
                                                     const float* __restrict__ bias,
                                                     float* __restrict__ out) {
    const int idx = blockIdx.x * 256 + threadIdx.x;   // MM*NN threads
    float s = bias[idx & (NN - 1)];
#pragma unroll 16
    for (int c = 0; c < KSPLIT; ++c)
        s += part[(size_t)c * (MM * NN) + idx];
    out[idx] = s;
}

// ---------------------------------------------------------------------------
// Fallback path (only if ws too small): bias-init + atomic gemm.
// ---------------------------------------------------------------------------
__global__ __launch_bounds__(256) void init_kernel(const float* __restrict__ bias,
                                                   float* __restrict__ out) {
    int idx = blockIdx.x * 256 + threadIdx.x;
    out[idx] = bias[idx & (NN - 1)];
}

__global__ __launch_bounds__(256, 8) void gemm_atomic(const float* __restrict__ W,
                                                      const float* __restrict__ wsinv,
                                                      const float* __restrict__ ws,
                                                      float* __restrict__ out) {
    const int tid = threadIdx.x;
    const int n   = blockIdx.x * 256 + tid;
    const int k0  = blockIdx.y * KC;

    __shared__ uint4 sxq[KC * MM / 8];
    if (tid < KC * MM / 8)
        sxq[tid] = ((const uint4*)((const unsigned short*)(ws + XQT_OFF) +
                                   (size_t)k0 * MM))[tid];
    __syncthreads();

    float acc[MM];
#pragma unroll
    for (int m = 0; m < MM; ++m) acc[m] = 0.0f;

    const float* __restrict__ Wp = W + (size_t)k0 * NN + n;
    for (int k = 0; k < KC; ++k) {
        float w = Wp[(size_t)k * NN];
        uint4 a = sxq[k];
        acc[0] = fmaf(w, __uint_as_float(a.x << 16),          acc[0]);
        acc[1] = fmaf(w, __uint_as_float(a.x & 0xFFFF0000u),  acc[1]);
        acc[2] = fmaf(w, __uint_as_float(a.y << 16),          acc[2]);
        acc[3] = fmaf(w, __uint_as_float(a.y & 0xFFFF0000u),  acc[3]);
        acc[4] = fmaf(w, __uint_as_float(a.z << 16),          acc[4]);
        acc[5] = fmaf(w, __uint_as_float(a.z & 0xFFFF0000u),  acc[5]);
        acc[6] = fmaf(w, __uint_as_float(a.w << 16),          acc[6]);
        acc[7] = fmaf(w, __uint_as_float(a.w & 0xFFFF0000u),  acc[7]);
    }

    const float wsn = wsinv[n];
#pragma unroll
    for (int m = 0; m < MM; ++m)
        unsafeAtomicAdd(out + (size_t)m * NN + n, acc[m] * (ws[m] * wsn));
}

extern "C" void kernel_launch(void* const* d_in, const int* in_sizes, int n_in,
                              void* d_out, int out_size, void* d_ws, size_t ws_size,
                              hipStream_t stream) {
    const float* x     = (const float*)d_in[0];   // [M,K] f32
    const float* W     = (const float*)d_in[1];   // [K,N] f32 (fp8 values)
    const float* wsinv = (const float*)d_in[2];   // [N]   f32
    const float* bias  = (const float*)d_in[3];   // [N]   f32
    float* out = (float*)d_out;                   // [M,N] f32
    float* ws  = (float*)d_ws;

    const size_t need = (size_t)(PART_OFF + (size_t)KSPLIT * MM * NN) * sizeof(float);

    prep_kernel<<<MM, 256, 0, stream>>>(x, ws);

    if (ws_size >= need) {
        float* part = ws + PART_OFF;
        gemm_partial<<<dim3(NN / 256, KSPLIT), 256, 0, stream>>>(W, wsinv, ws, part);
        reduce_kernel<<<(MM * NN) / 256, 256, 0, stream>>>(part, bias, out);
    } else {
        init_kernel<<<(MM * NN) / 256, 256, 0, stream>>>(bias, out);
        gemm_atomic<<<dim3(NN / 256, KSPLIT), 256, 0, stream>>>(W, wsinv, ws, out);
    }
}

// Round 9
// 71.613 us; speedup vs baseline: 4.4831x; 4.4831x over previous
//
#include <hip/hip_runtime.h>
#include <stdint.h>

#define MM 8
#define KK 8192
#define NN 8192
#define KC 64                  // k rows per gemm block
#define KSPLIT (KK / KC)       // 128 partial slabs
#define G 8                    // k-steps per prefetch group (8 KB/wave in flight)
#define FP8MAXV 448.0f

typedef float f32x4 __attribute__((ext_vector_type(4)));

// ws layout (floats):
//   [0..7]                    x_scale_inv per row
//   [64 .. 64+KK*MM)          xqT transposed quantized activations [k][m] (f32)
//   [PART_OFF ..)             partials [KSPLIT][MM][NN]  (32 MB)
#define XQT_OFF 64
#define PART_OFF (XQT_OFF + KK * MM)

// ---------------------------------------------------------------------------
// Bit-exact RNE f32 -> fp8 e4m3fn -> f32 (|v| <= 448).
// ---------------------------------------------------------------------------
__device__ __forceinline__ float fp8_e4m3_round(float v) {
    uint32_t u = __float_as_uint(v);
    uint32_t mag = u & 0x7fffffffu;
    if (mag >= 0x3C800000u) {            // |v| >= 2^-6 : normal e4m3
        uint32_t lsb = (u >> 20) & 1u;
        uint32_t r = u + 0x0007FFFFu + lsb;
        r &= 0xFFF00000u;
        return __uint_as_float(r);
    }
    return rintf(v * 512.0f) * (1.0f / 512.0f);   // subnormal quantum 2^-9
}

// ---------------------------------------------------------------------------
// Kernel 1: per-row amax -> scale; quantize x; store xqT[k][m] (f32).
// ---------------------------------------------------------------------------
__global__ __launch_bounds__(256) void prep_kernel(const float* __restrict__ x,
                                                   float* __restrict__ ws) {
    const int m = blockIdx.x;
    const int tid = threadIdx.x;
    const float* row = x + (size_t)m * KK;

    float amax = 0.0f;
    for (int k = tid * 4; k < KK; k += 256 * 4) {
        f32x4 v = *(const f32x4*)(row + k);
        amax = fmaxf(amax, fmaxf(fmaxf(fabsf(v.x), fabsf(v.y)),
                                 fmaxf(fabsf(v.z), fabsf(v.w))));
    }
#pragma unroll
    for (int off = 32; off >= 1; off >>= 1)
        amax = fmaxf(amax, __shfl_xor(amax, off, 64));

    __shared__ float sred[4];
    __shared__ float sscale;
    if ((tid & 63) == 0) sred[tid >> 6] = amax;
    __syncthreads();
    if (tid == 0) {
        float a = fmaxf(fmaxf(sred[0], sred[1]), fmaxf(sred[2], sred[3]));
        float scale = (a > 0.0f) ? (FP8MAXV / a) : 1.0f;
        sscale = scale;
        ws[m] = 1.0f / scale;
    }
    __syncthreads();
    const float scale = sscale;

    float* xqT = ws + XQT_OFF;
    for (int k = tid; k < KK; k += 256)
        xqT[(size_t)k * MM + m] = fp8_e4m3_round(row[k] * scale);
}

// ---------------------------------------------------------------------------
// Kernel 2 (R8): deep-pipeline split-K GEMV. 4 cols/thread (dwordx4 W loads,
// 1 KiB/wave-instr). KC=64, grid (NN/1024, KSPLIT) = (8,128) = 1024 blocks =
// 4 blocks/CU = 16 waves/CU. G=8 register double-buffer: 8 outstanding
// dwordx4 loads (8 KB/wave) through every compute phase -> 128 KB/CU in
// flight (4x all previous rounds; tests the latency-starvation hypothesis).
// LB(256,4): VGPR cap 128, budget ~111 -> no starvation (R7 failure mode),
// no spill. Activations from LDS (lgkmcnt path, R4 failure mode avoided).
// ---------------------------------------------------------------------------
__global__ __launch_bounds__(256, 4) void gemm_partial(const float* __restrict__ W,
                                                       const float* __restrict__ wsinv,
                                                       const float* __restrict__ ws,
                                                       float* __restrict__ part) {
    const int tid = threadIdx.x;
    const int n4  = (blockIdx.x * 256 + tid) * 4;
    const int c   = blockIdx.y;
    const int k0  = c * KC;

    __shared__ f32x4 sxq[KC * MM / 4];   // 2 KB: [k][half], half=0: m0..3, 1: m4..7
    if (tid < KC * MM / 4)
        sxq[tid] = ((const f32x4*)(ws + XQT_OFF + (size_t)k0 * MM))[tid];

    const f32x4 xs0 = *(const f32x4*)(ws);        // x_scale_inv[0..3]
    const f32x4 xs1 = *(const f32x4*)(ws + 4);    // x_scale_inv[4..7]
    const f32x4 wsn = *(const f32x4*)(wsinv + n4);
    __syncthreads();

    f32x4 acc[MM];
#pragma unroll
    for (int m = 0; m < MM; ++m) acc[m] = (f32x4)0.0f;

    const float* __restrict__ Wp = W + (size_t)k0 * NN + n4;

    f32x4 wA[G], wB[G];
    auto loadg = [&](f32x4 (&buf)[G], int kbase) {
#pragma unroll
        for (int j = 0; j < G; ++j)
            buf[j] = *(const f32x4*)(Wp + (size_t)(kbase + j) * NN);
    };
    auto compute = [&](f32x4 (&buf)[G], int kbase) {
#pragma unroll
        for (int j = 0; j < G; ++j) {
            f32x4 a0 = sxq[(kbase + j) * 2 + 0];   // ds_read_b128 broadcast
            f32x4 a1 = sxq[(kbase + j) * 2 + 1];
            f32x4 w  = buf[j];
            acc[0] += w * a0.x;
            acc[1] += w * a0.y;
            acc[2] += w * a0.z;
            acc[3] += w * a0.w;
            acc[4] += w * a1.x;
            acc[5] += w * a1.y;
            acc[6] += w * a1.z;
            acc[7] += w * a1.w;
        }
    };

    loadg(wA, 0 * G);
    loadg(wB, 1 * G);
    int g = 0;
    for (; g + 2 < KC / G; g += 2) {               // KC/G = 8 groups
        compute(wA, (g + 0) * G);
        loadg(wA, (g + 2) * G);
        compute(wB, (g + 1) * G);
        loadg(wB, (g + 3) * G);
    }
    compute(wA, (g + 0) * G);
    compute(wB, (g + 1) * G);

    float xsa[MM] = {xs0.x, xs0.y, xs0.z, xs0.w, xs1.x, xs1.y, xs1.z, xs1.w};
    float* p = part + ((size_t)c * MM) * NN + n4;
#pragma unroll
    for (int m = 0; m < MM; ++m)
        *(f32x4*)(p + (size_t)m * NN) = acc[m] * (xsa[m] * wsn);
}

// ---------------------------------------------------------------------------
// Kernel 3: reduce KSPLIT partials + bias -> out. One output/thread.
// ---------------------------------------------------------------------------
__global__ __launch_bounds__(256) void reduce_kernel(const float* __restrict__ part,
                                                     const float* __restrict__ bias,
                                                     float* __restrict__ out) {
    const int idx = blockIdx.x * 256 + threadIdx.x;   // MM*NN threads
    float s = bias[idx & (NN - 1)];
#pragma unroll 16
    for (int c = 0; c < KSPLIT; ++c)
        s += part[(size_t)c * (MM * NN) + idx];
    out[idx] = s;
}

// ---------------------------------------------------------------------------
// Fallback path (only if ws too small): bias-init + atomic gemm.
// ---------------------------------------------------------------------------
__global__ __launch_bounds__(256) void init_kernel(const float* __restrict__ bias,
                                                   float* __restrict__ out) {
    int idx = blockIdx.x * 256 + threadIdx.x;
    out[idx] = bias[idx & (NN - 1)];
}

__global__ __launch_bounds__(256, 4) void gemm_atomic(const float* __restrict__ W,
                                                      const float* __restrict__ wsinv,
                                                      const float* __restrict__ ws,
                                                      float* __restrict__ out) {
    const int tid = threadIdx.x;
    const int n4  = (blockIdx.x * 256 + tid) * 4;
    const int k0  = blockIdx.y * KC;

    __shared__ f32x4 sxq[KC * MM / 4];
    if (tid < KC * MM / 4)
        sxq[tid] = ((const f32x4*)(ws + XQT_OFF + (size_t)k0 * MM))[tid];
    const f32x4 xs0 = *(const f32x4*)(ws);
    const f32x4 xs1 = *(const f32x4*)(ws + 4);
    const f32x4 wsn = *(const f32x4*)(wsinv + n4);
    __syncthreads();

    f32x4 acc[MM];
#pragma unroll
    for (int m = 0; m < MM; ++m) acc[m] = (f32x4)0.0f;

    const float* __restrict__ Wp = W + (size_t)k0 * NN + n4;
    for (int k = 0; k < KC; ++k) {
        f32x4 w  = *(const f32x4*)(Wp + (size_t)k * NN);
        f32x4 a0 = sxq[k * 2 + 0];
        f32x4 a1 = sxq[k * 2 + 1];
        acc[0] += w * a0.x;  acc[1] += w * a0.y;
        acc[2] += w * a0.z;  acc[3] += w * a0.w;
        acc[4] += w * a1.x;  acc[5] += w * a1.y;
        acc[6] += w * a1.z;  acc[7] += w * a1.w;
    }

    float xsa[MM] = {xs0.x, xs0.y, xs0.z, xs0.w, xs1.x, xs1.y, xs1.z, xs1.w};
#pragma unroll
    for (int m = 0; m < MM; ++m) {
        f32x4 r = acc[m] * (xsa[m] * wsn);
        float* o = out + (size_t)m * NN + n4;
        unsafeAtomicAdd(o + 0, r.x);
        unsafeAtomicAdd(o + 1, r.y);
        unsafeAtomicAdd(o + 2, r.z);
        unsafeAtomicAdd(o + 3, r.w);
    }
}

extern "C" void kernel_launch(void* const* d_in, const int* in_sizes, int n_in,
                              void* d_out, int out_size, void* d_ws, size_t ws_size,
                              hipStream_t stream) {
    const float* x     = (const float*)d_in[0];   // [M,K] f32
    const float* W     = (const float*)d_in[1];   // [K,N] f32 (fp8 values)
    const float* wsinv = (const float*)d_in[2];   // [N]   f32
    const float* bias  = (const float*)d_in[3];   // [N]   f32
    float* out = (float*)d_out;                   // [M,N] f32
    float* ws  = (float*)d_ws;

    const size_t need = (size_t)(PART_OFF + (size_t)KSPLIT * MM * NN) * sizeof(float);

    prep_kernel<<<MM, 256, 0, stream>>>(x, ws);

    if (ws_size >= need) {
        float* part = ws + PART_OFF;
        gemm_partial<<<dim3(NN / 1024, KSPLIT), 256, 0, stream>>>(W, wsinv, ws, part);
        reduce_kernel<<<(MM * NN) / 256, 256, 0, stream>>>(part, bias, out);
    } else {
        init_kernel<<<(MM * NN) / 256, 256, 0, stream>>>(bias, out);
        gemm_atomic<<<dim3(NN / 1024, KSPLIT), 256, 0, stream>>>(W, wsinv, ws, out);
    }
}